// Round 6
// baseline (390.094 us; speedup 1.0000x reference)
//
#include <hip/hip_runtime.h>

#define NN 50000
#define NE 640000
#define NPAD 50176   // 196*256
#define SCAN_B 196   // ceil(NN/256)

typedef short bf16x8 __attribute__((ext_vector_type(8)));
typedef float f32x4 __attribute__((ext_vector_type(4)));

__device__ __forceinline__ unsigned short f2bf(float f) {
  unsigned int u = __float_as_uint(f);
  unsigned int r = (u + 0x7FFFu + ((u >> 16) & 1u)) >> 16;
  return (unsigned short)r;
}
__device__ __forceinline__ float bf2f(unsigned short h) {
  return __uint_as_float(((unsigned int)h) << 16);
}

typedef const __attribute__((address_space(1))) void* gptr_t;
typedef __attribute__((address_space(3))) void* lptr_t;
__device__ __forceinline__ void gload16(const void* g, void* l) {
  __builtin_amdgcn_global_load_lds((gptr_t)g, (lptr_t)l, 16, 0, 0);
}

// ---------------- degree histogram + per-edge replica rank ----------------
// 8 XCD-keyed replicas: atomics to a replica are issued (empirically) from one
// XCD only -> line stays in that XCD's L2. Correct regardless of mapping.
__global__ __launch_bounds__(256) void k_deg(const int* __restrict__ src,
                                             const int* __restrict__ dst,
                                             int* __restrict__ rep_out,
                                             int* __restrict__ rep_in,
                                             int* __restrict__ rank) {
  int e = blockIdx.x * 256 + threadIdx.x;
  int r = blockIdx.x & 7;
  if (e < NE) {
    atomicAdd(&rep_out[r * NPAD + src[e]], 1);
    rank[e] = atomicAdd(&rep_in[r * NPAD + dst[e]], 1);
  }
}

// ---------------- scan stage 1: replica-sum, norms, per-node replica prefix ----------------
__global__ __launch_bounds__(256) void k_scan1(const int* __restrict__ rep_out,
                                               const int* __restrict__ rep_in,
                                               float* __restrict__ nsrc,
                                               float* __restrict__ ndst,
                                               int* __restrict__ in_cnt,
                                               int* __restrict__ repoff,
                                               int* __restrict__ bsum) {
  int t = threadIdx.x, n = blockIdx.x * 256 + t;
  int tot_in = 0;
  if (n < NN) {
    int od = 0;
#pragma unroll
    for (int r = 0; r < 8; ++r) od += rep_out[r * NPAD + n];
    int pf = 0;
#pragma unroll
    for (int r = 0; r < 8; ++r) {
      repoff[n * 8 + r] = pf;
      pf += rep_in[r * NPAD + n];
    }
    tot_in = pf;
    in_cnt[n] = tot_in;
    nsrc[n] = 1.0f / sqrtf((float)max(od, 1));
    ndst[n] = 1.0f / sqrtf((float)max(tot_in, 1));
  }
  int s = tot_in;
#pragma unroll
  for (int o = 32; o >= 1; o >>= 1) s += __shfl_down(s, o);
  __shared__ int ws4[4];
  if ((t & 63) == 0) ws4[t >> 6] = s;
  __syncthreads();
  if (t == 0) bsum[blockIdx.x] = ws4[0] + ws4[1] + ws4[2] + ws4[3];
}

// ---------------- scan stage 2+3 fused: row_start ----------------
__global__ __launch_bounds__(256) void k_scan3(const int* __restrict__ in_cnt,
                                               const int* __restrict__ bsum,
                                               int* __restrict__ row_start) {
  int b = blockIdx.x, t = threadIdx.x, lane = t & 63, w = t >> 6;
  __shared__ int wtot[4];
  __shared__ int sbase;
  {
    int v = (t < b) ? bsum[t] : 0;
#pragma unroll
    for (int o = 32; o >= 1; o >>= 1) v += __shfl_down(v, o);
    if (lane == 0) wtot[w] = v;
    __syncthreads();
    if (t == 0) sbase = wtot[0] + wtot[1] + wtot[2] + wtot[3];
    __syncthreads();
  }
  int i = b * 256 + t;
  int v = (i < NN) ? in_cnt[i] : 0;
  int sc = v;
#pragma unroll
  for (int o = 1; o < 64; o <<= 1) {
    int x = __shfl_up(sc, o);
    if (lane >= o) sc += x;
  }
  if (lane == 63) wtot[w] = sc;
  __syncthreads();
  int base = sbase;
  for (int j = 0; j < w; ++j) base += wtot[j];
  if (i < NN) row_start[i] = base + sc - v;
}

// ---------------- CSR fill (atomic-free via replica rank) ----------------
__global__ __launch_bounds__(256) void k_fill(const int* __restrict__ src,
                                              const int* __restrict__ dst,
                                              const int* __restrict__ row_start,
                                              const int* __restrict__ repoff,
                                              const int* __restrict__ rank,
                                              int* __restrict__ col) {
  int e = blockIdx.x * 256 + threadIdx.x;
  int r = blockIdx.x & 7;  // same mapping as k_deg
  if (e < NE) {
    int d = dst[e];
    col[row_start[d] + repoff[d * 8 + r] + rank[e]] = src[e];
  }
}

// ---------------- fused embed + weight prep ----------------
__global__ __launch_bounds__(256) void k_embed_prep(const float* __restrict__ nf,
                                                    const float* __restrict__ W,
                                                    const float* __restrict__ b,
                                                    const float* __restrict__ nsrc,
                                                    float* __restrict__ xs,
                                                    const float* __restrict__ Wg,
                                                    const float* __restrict__ Wo1,
                                                    unsigned short* __restrict__ wt) {
  int bid = blockIdx.x;
  if (bid < 25000) {
    int idx = bid * 256 + threadIdx.x;
    int n = idx >> 7, j = idx & 127;
    const float* f = nf + n * 4;
    float acc = b[j];
    acc += f[0] * W[j] + f[1] * W[128 + j] + f[2] * W[256 + j] + f[3] * W[384 + j];
    xs[idx] = acc * nsrc[n];
  } else {
    int idx = (bid - 25000) * 256 + threadIdx.x;  // 4 * 16384
    int mat = idx >> 14, rem = idx & 16383;
    int k = rem >> 7, n = rem & 127;
    const float* Wsrc = (mat < 3) ? (Wg + mat * 16384) : Wo1;
    float v = Wsrc[k * 128 + n];
    unsigned short hi = f2bf(v);
    float lo = v - bf2f(hi);
    unsigned short* base = wt + mat * 32768;
    base[n * 128 + k] = hi;
    base[16384 + n * 128 + k] = f2bf(lo);
  }
}

// ---------------- SpMM: a[n] = ndst[n]*sum xs[src]; write bf16 hi/lo split ----------------
__global__ __launch_bounds__(256) void k_spmm(const float* __restrict__ xs,
                                              unsigned short* __restrict__ ahi,
                                              unsigned short* __restrict__ alo,
                                              const int* __restrict__ col,
                                              const int* __restrict__ row_start,
                                              const int* __restrict__ in_cnt,
                                              const float* __restrict__ ndst) {
  int node = blockIdx.x * 4 + (threadIdx.x >> 6);
  int lane = threadIdx.x & 63;
  int half = lane >> 5;
  int ql = lane & 31;
  int start = row_start[node];
  int cnt = in_cnt[node];
  float4 acc = make_float4(0.f, 0.f, 0.f, 0.f);
  const float4* X4 = (const float4*)xs;
  for (int base = 0; base < cnt; base += 64) {
    int m = min(cnt - base, 64);
    int ccol = (lane < m) ? col[start + base + lane] : 0;
    for (int jj = 0; jj < m; jj += 8) {
      int i0 = jj + half, i1 = i0 + 2, i2 = i0 + 4, i3 = i0 + 6;
      int mm = m - 1;
      int s0 = __shfl(ccol, min(i0, mm));
      int s1 = __shfl(ccol, min(i1, mm));
      int s2 = __shfl(ccol, min(i2, mm));
      int s3 = __shfl(ccol, min(i3, mm));
      float f0 = (i0 < m) ? 1.f : 0.f;
      float f1 = (i1 < m) ? 1.f : 0.f;
      float f2 = (i2 < m) ? 1.f : 0.f;
      float f3 = (i3 < m) ? 1.f : 0.f;
      float4 v0 = X4[(size_t)s0 * 32 + ql];
      float4 v1 = X4[(size_t)s1 * 32 + ql];
      float4 v2 = X4[(size_t)s2 * 32 + ql];
      float4 v3 = X4[(size_t)s3 * 32 + ql];
      acc.x = fmaf(f0, v0.x, acc.x); acc.y = fmaf(f0, v0.y, acc.y);
      acc.z = fmaf(f0, v0.z, acc.z); acc.w = fmaf(f0, v0.w, acc.w);
      acc.x = fmaf(f1, v1.x, acc.x); acc.y = fmaf(f1, v1.y, acc.y);
      acc.z = fmaf(f1, v1.z, acc.z); acc.w = fmaf(f1, v1.w, acc.w);
      acc.x = fmaf(f2, v2.x, acc.x); acc.y = fmaf(f2, v2.y, acc.y);
      acc.z = fmaf(f2, v2.z, acc.z); acc.w = fmaf(f2, v2.w, acc.w);
      acc.x = fmaf(f3, v3.x, acc.x); acc.y = fmaf(f3, v3.y, acc.y);
      acc.z = fmaf(f3, v3.z, acc.z); acc.w = fmaf(f3, v3.w, acc.w);
    }
  }
  acc.x += __shfl_down(acc.x, 32);
  acc.y += __shfl_down(acc.y, 32);
  acc.z += __shfl_down(acc.z, 32);
  acc.w += __shfl_down(acc.w, 32);
  if (half == 0) {
    float nd = ndst[node];
    float v0 = acc.x * nd, v1 = acc.y * nd, v2 = acc.z * nd, v3 = acc.w * nd;
    ushort4 h, l;
    h.x = f2bf(v0); l.x = f2bf(v0 - bf2f(h.x));
    h.y = f2bf(v1); l.y = f2bf(v1 - bf2f(h.y));
    h.z = f2bf(v2); l.z = f2bf(v2 - bf2f(h.z));
    h.w = f2bf(v3); l.w = f2bf(v3 - bf2f(h.w));
    *(ushort4*)(ahi + (size_t)node * 128 + ql * 4) = h;
    *(ushort4*)(alo + (size_t)node * 128 + ql * 4) = l;
  }
}

// ---------------- MFMA GEMM (bf16x3 split): out = relu(A @ Wt^T + bias) ----------------
// modes: 0 = write fp32 * nsrc (xs), 1 = write bf16 hi/lo, 3 = fused final dot with W_o2
__global__ __launch_bounds__(256) void k_gemm_mfma(
    const unsigned short* __restrict__ Ahi, const unsigned short* __restrict__ Alo,
    const unsigned short* __restrict__ Wth, const unsigned short* __restrict__ Wtl,
    const float* __restrict__ bias, float* __restrict__ outf,
    unsigned short* __restrict__ outhi, unsigned short* __restrict__ outlo,
    const float* __restrict__ nsrc, const float* __restrict__ W_o2,
    const float* __restrict__ b_o2, int M, int mode) {
  __shared__ unsigned short sm[2 * 64 * 128];  // Ah (16KB) then Al (16KB)
  __shared__ float smred[4][64];
  int tid = threadIdx.x;
  int lane = tid & 63, w = tid >> 6;
  int tile0 = blockIdx.x * 64;

  {
    int slot = lane & 15;
#pragma unroll
    for (int j = 0; j < 4; ++j) {
      int ldsoff = w * 4096 + j * 1024;
      int row = (ldsoff >> 8) + (lane >> 4);
      int grow = tile0 + row;
      if (grow > M - 1) grow = M - 1;
      size_t gsrc = (size_t)grow * 256 + (size_t)(((slot ^ (row & 7)) << 4));
      gload16((const char*)Ahi + gsrc, (char*)sm + ldsoff);
      gload16((const char*)Alo + gsrc, (char*)sm + 16384 + ldsoff);
    }
  }

  bf16x8 bh[2][4], bl[2][4];
  {
    int koff = (lane >> 4) * 8;
#pragma unroll
    for (int cf = 0; cf < 2; ++cf) {
      int n = w * 32 + cf * 16 + (lane & 15);
      const unsigned short* ph = Wth + (size_t)n * 128 + koff;
      const unsigned short* pl = Wtl + (size_t)n * 128 + koff;
#pragma unroll
      for (int kc = 0; kc < 4; ++kc) {
        bh[cf][kc] = *(const bf16x8*)(ph + kc * 32);
        bl[cf][kc] = *(const bf16x8*)(pl + kc * 32);
      }
    }
  }

  f32x4 acc[4][2] = {};
  __syncthreads();

  int r15 = lane & 15, kq = lane >> 4;
  for (int kc = 0; kc < 4; ++kc) {
    bf16x8 ah[4], al[4];
#pragma unroll
    for (int m = 0; m < 4; ++m) {
      int row = m * 16 + r15;
      int boff = row * 256 + ((((kc * 4 + kq) ^ (row & 7))) << 4);
      ah[m] = *(const bf16x8*)((const char*)sm + boff);
      al[m] = *(const bf16x8*)((const char*)sm + 16384 + boff);
    }
#pragma unroll
    for (int m = 0; m < 4; ++m)
#pragma unroll
      for (int cf = 0; cf < 2; ++cf) {
        acc[m][cf] = __builtin_amdgcn_mfma_f32_16x16x32_bf16(ah[m], bh[cf][kc], acc[m][cf], 0, 0, 0);
        acc[m][cf] = __builtin_amdgcn_mfma_f32_16x16x32_bf16(ah[m], bl[cf][kc], acc[m][cf], 0, 0, 0);
        acc[m][cf] = __builtin_amdgcn_mfma_f32_16x16x32_bf16(al[m], bh[cf][kc], acc[m][cf], 0, 0, 0);
      }
  }

  if (mode == 3) {
    float w2v[2], bv2[2];
#pragma unroll
    for (int cf = 0; cf < 2; ++cf) {
      int colg = w * 32 + cf * 16 + r15;
      w2v[cf] = W_o2[colg];
      bv2[cf] = bias[colg];
    }
#pragma unroll
    for (int m = 0; m < 4; ++m) {
#pragma unroll
      for (int i = 0; i < 4; ++i) {
        float p = fmaxf(acc[m][0][i] + bv2[0], 0.f) * w2v[0] +
                  fmaxf(acc[m][1][i] + bv2[1], 0.f) * w2v[1];
#pragma unroll
        for (int msk = 1; msk < 16; msk <<= 1) p += __shfl_xor(p, msk);
        if (r15 == 0) smred[w][m * 16 + kq * 4 + i] = p;
      }
    }
    __syncthreads();
    if (tid < 64) {
      int gr = tile0 + tid;
      if (gr < M)
        outf[gr] = smred[0][tid] + smred[1][tid] + smred[2][tid] + smred[3][tid] + b_o2[0];
    }
    return;
  }
#pragma unroll
  for (int cf = 0; cf < 2; ++cf) {
    int colg = w * 32 + cf * 16 + r15;
    float bv = bias[colg];
#pragma unroll
    for (int m = 0; m < 4; ++m) {
#pragma unroll
      for (int i = 0; i < 4; ++i) {
        int gr = tile0 + m * 16 + kq * 4 + i;
        if (gr < M) {
          float v = fmaxf(acc[m][cf][i] + bv, 0.f);
          if (mode == 0) {
            outf[(size_t)gr * 128 + colg] = v * nsrc[gr];
          } else {
            unsigned short h = f2bf(v);
            outhi[(size_t)gr * 128 + colg] = h;
            outlo[(size_t)gr * 128 + colg] = f2bf(v - bf2f(h));
          }
        }
      }
    }
  }
}

extern "C" void kernel_launch(void* const* d_in, const int* in_sizes, int n_in,
                              void* d_out, int out_size, void* d_ws, size_t ws_size,
                              hipStream_t stream) {
  const float* node_feats = (const float*)d_in[0];
  const int* src = (const int*)d_in[1];
  const int* dst = (const int*)d_in[2];
  const float* W_emb = (const float*)d_in[3];
  const float* b_emb = (const float*)d_in[4];
  const float* W_g = (const float*)d_in[5];
  const float* b_g = (const float*)d_in[6];
  const float* W_o1 = (const float*)d_in[7];
  const float* b_o1 = (const float*)d_in[8];
  const float* W_o2 = (const float*)d_in[9];
  const float* b_o2 = (const float*)d_in[10];
  float* out = (float*)d_out;

  // Workspace layout (bytes). NB round-5 bug: replica arrays are 8*NPAD*4 =
  // 1,605,632 BYTES each (not 401,408 — that was the element count).
  char* ws = (char*)d_ws;
  int* rep_out   = (int*)(ws + 0);                        // 1,605,632 B
  int* rep_in    = (int*)(ws + 1605632);                  // 1,605,632 B
  int* in_cnt    = (int*)(ws + 3211264);                  // 200,704 B
  int* row_start = (int*)(ws + 3411968);                  // 200,704 B
  float* nsrc    = (float*)(ws + 3612672);                // 200,704 B
  float* ndst    = (float*)(ws + 3813376);                // 200,704 B
  int* repoff    = (int*)(ws + 4014080);                  // 1,605,632 B
  int* bsum      = (int*)(ws + 5619712);                  // 1,024 B
  int* col       = (int*)(ws + 5620736);                  // 2,560,000 B
  unsigned short* wt = (unsigned short*)(ws + 8180736);   // 262,144 B
  float* X       = (float*)(ws + 8442880);                // 25.6 MB
  unsigned short* Xu = (unsigned short*)(ws + 8442880);
  int* rank      = (int*)(ws + 8442880);                  // aliases X (dead before embed)
  unsigned short* Ahi = (unsigned short*)(ws + 34042880); // 12.8 MB
  unsigned short* Alo = (unsigned short*)(ws + 46842880); // 12.8 MB -> ends 59,642,880

  hipMemsetAsync(d_ws, 0, 3211264, stream);  // rep_out + rep_in

  k_deg<<<(NE + 255) / 256, 256, 0, stream>>>(src, dst, rep_out, rep_in, rank);
  k_scan1<<<SCAN_B, 256, 0, stream>>>(rep_out, rep_in, nsrc, ndst, in_cnt, repoff, bsum);
  k_scan3<<<SCAN_B, 256, 0, stream>>>(in_cnt, bsum, row_start);
  k_fill<<<(NE + 255) / 256, 256, 0, stream>>>(src, dst, row_start, repoff, rank, col);
  k_embed_prep<<<25256, 256, 0, stream>>>(node_feats, W_emb, b_emb, nsrc, X,
                                          W_g, W_o1, wt);

  int gemm_grid = (NN + 63) / 64;
  for (int l = 0; l < 3; ++l) {
    k_spmm<<<NN / 4, 256, 0, stream>>>(X, Ahi, Alo, col, row_start, in_cnt, ndst);
    unsigned short* wth = wt + l * 32768;
    unsigned short* wtl = wth + 16384;
    if (l < 2) {
      k_gemm_mfma<<<gemm_grid, 256, 0, stream>>>(Ahi, Alo, wth, wtl, b_g + l * 128,
                                                 X, nullptr, nullptr, nsrc,
                                                 nullptr, nullptr, NN, 0);
    } else {
      k_gemm_mfma<<<gemm_grid, 256, 0, stream>>>(Ahi, Alo, wth, wtl, b_g + l * 128,
                                                 nullptr, Xu, Xu + 6400000, nsrc,
                                                 nullptr, nullptr, NN, 1);
    }
  }
  k_gemm_mfma<<<gemm_grid, 256, 0, stream>>>(Xu, Xu + 6400000, wt + 3 * 32768,
                                             wt + 3 * 32768 + 16384, b_o1,
                                             out, nullptr, nullptr, nsrc,
                                             W_o2, b_o2, NN, 3);
}

// Round 7
// 361.589 us; speedup vs baseline: 1.0788x; 1.0788x over previous
//
#include <hip/hip_runtime.h>

#define NN 50000
#define NE 640000
#define NPAD 50176     // even; 196*256
#define SCAN_B 196     // ceil(NN/256)
#define OUT_CHUNKS 64
#define OUT_CE 10000   // 64*10000 = 640000
#define IN_CHUNKS 128
#define IN_CE 5000     // 128*5000 = 640000

typedef short bf16x8 __attribute__((ext_vector_type(8)));
typedef float f32x4 __attribute__((ext_vector_type(4)));

__device__ __forceinline__ unsigned short f2bf(float f) {
  unsigned int u = __float_as_uint(f);
  unsigned int r = (u + 0x7FFFu + ((u >> 16) & 1u)) >> 16;
  return (unsigned short)r;
}
__device__ __forceinline__ float bf2f(unsigned short h) {
  return __uint_as_float(((unsigned int)h) << 16);
}

typedef const __attribute__((address_space(1))) void* gptr_t;
typedef __attribute__((address_space(3))) void* lptr_t;
__device__ __forceinline__ void gload16(const void* g, void* l) {
  __builtin_amdgcn_global_load_lds((gptr_t)g, (lptr_t)l, 16, 0, 0);
}

// ---------------- LDS histogram: no global atomics ----------------
// blocks [0,64): out-degree histogram of src chunk b (10000 edges)
// blocks [64,192): in-degree histogram of dst chunk b-64 (5000 edges)
// Packed u16 counters in LDS (100,352 B); per-chunk count < 65536 always.
__global__ __launch_bounds__(256) void k_hist(const int* __restrict__ src,
                                              const int* __restrict__ dst,
                                              unsigned short* __restrict__ hist_out,
                                              unsigned short* __restrict__ hist_in) {
  __shared__ unsigned int h[NPAD / 2];
  int b = blockIdx.x, tid = threadIdx.x;
  for (int i = tid; i < NPAD / 2; i += 256) h[i] = 0;
  __syncthreads();
  if (b < OUT_CHUNKS) {
    int base = b * OUT_CE;
    for (int i = tid; i < OUT_CE; i += 256) {
      int n = src[base + i];
      atomicAdd(&h[n >> 1], (n & 1) ? 0x10000u : 1u);
    }
  } else {
    int base = (b - OUT_CHUNKS) * IN_CE;
    for (int i = tid; i < IN_CE; i += 256) {
      int n = dst[base + i];
      atomicAdd(&h[n >> 1], (n & 1) ? 0x10000u : 1u);
    }
  }
  __syncthreads();
  unsigned int* outp = (unsigned int*)((b < OUT_CHUNKS ? hist_out : hist_in) +
                                       (size_t)(b < OUT_CHUNKS ? b : b - OUT_CHUNKS) * NPAD);
  for (int i = tid; i < NPAD / 2; i += 256) outp[i] = h[i];
}

// ---------------- scan1: degree sums, norms, in-place chunk prefixes ----------------
__global__ __launch_bounds__(256) void k_scan1(const unsigned short* __restrict__ hist_out,
                                               unsigned short* __restrict__ hist_in,
                                               float* __restrict__ nsrc,
                                               float* __restrict__ ndst,
                                               int* __restrict__ in_cnt,
                                               int* __restrict__ bsum) {
  int t = threadIdx.x, n = blockIdx.x * 256 + t;
  int tot_in = 0;
  if (n < NN) {
    int od = 0;
#pragma unroll 8
    for (int c = 0; c < OUT_CHUNKS; ++c) od += hist_out[(size_t)c * NPAD + n];
    int pf = 0;
#pragma unroll 8
    for (int c = 0; c < IN_CHUNKS; ++c) {
      size_t idx = (size_t)c * NPAD + n;
      unsigned short v = hist_in[idx];
      hist_in[idx] = (unsigned short)pf;  // exclusive prefix over chunks
      pf += v;
    }
    tot_in = pf;
    in_cnt[n] = tot_in;
    nsrc[n] = 1.0f / sqrtf((float)max(od, 1));
    ndst[n] = 1.0f / sqrtf((float)max(tot_in, 1));
  }
  int s = tot_in;
#pragma unroll
  for (int o = 32; o >= 1; o >>= 1) s += __shfl_down(s, o);
  __shared__ int ws4[4];
  if ((t & 63) == 0) ws4[t >> 6] = s;
  __syncthreads();
  if (t == 0) bsum[blockIdx.x] = ws4[0] + ws4[1] + ws4[2] + ws4[3];
}

// ---------------- scan3: row_start ----------------
__global__ __launch_bounds__(256) void k_scan3(const int* __restrict__ in_cnt,
                                               const int* __restrict__ bsum,
                                               int* __restrict__ row_start) {
  int b = blockIdx.x, t = threadIdx.x, lane = t & 63, w = t >> 6;
  __shared__ int wtot[4];
  __shared__ int sbase;
  {
    int v = (t < b) ? bsum[t] : 0;
#pragma unroll
    for (int o = 32; o >= 1; o >>= 1) v += __shfl_down(v, o);
    if (lane == 0) wtot[w] = v;
    __syncthreads();
    if (t == 0) sbase = wtot[0] + wtot[1] + wtot[2] + wtot[3];
    __syncthreads();
  }
  int i = b * 256 + t;
  int v = (i < NN) ? in_cnt[i] : 0;
  int sc = v;
#pragma unroll
  for (int o = 1; o < 64; o <<= 1) {
    int x = __shfl_up(sc, o);
    if (lane >= o) sc += x;
  }
  if (lane == 63) wtot[w] = sc;
  __syncthreads();
  int base = sbase;
  for (int j = 0; j < w; ++j) base += wtot[j];
  if (i < NN) row_start[i] = base + sc - v;
}

// ---------------- CSR fill: LDS re-histogram gives local rank, no atomics ----------------
__global__ __launch_bounds__(256) void k_fill(const int* __restrict__ src,
                                              const int* __restrict__ dst,
                                              const int* __restrict__ row_start,
                                              const unsigned short* __restrict__ prefix,
                                              int* __restrict__ col) {
  __shared__ unsigned int h[NPAD / 2];
  int c = blockIdx.x, tid = threadIdx.x;
  for (int i = tid; i < NPAD / 2; i += 256) h[i] = 0;
  __syncthreads();
  int base = c * IN_CE;
  for (int i = tid; i < IN_CE; i += 256) {
    int d = dst[base + i];
    unsigned int old = atomicAdd(&h[d >> 1], (d & 1) ? 0x10000u : 1u);
    int rank = (d & 1) ? (int)(old >> 16) : (int)(old & 0xFFFFu);
    col[row_start[d] + (int)prefix[(size_t)c * NPAD + d] + rank] = src[base + i];
  }
}

// ---------------- fused embed + weight prep ----------------
__global__ __launch_bounds__(256) void k_embed_prep(const float* __restrict__ nf,
                                                    const float* __restrict__ W,
                                                    const float* __restrict__ b,
                                                    const float* __restrict__ nsrc,
                                                    float* __restrict__ xs,
                                                    const float* __restrict__ Wg,
                                                    const float* __restrict__ Wo1,
                                                    unsigned short* __restrict__ wt) {
  int bid = blockIdx.x;
  if (bid < 25000) {
    int idx = bid * 256 + threadIdx.x;
    int n = idx >> 7, j = idx & 127;
    const float* f = nf + n * 4;
    float acc = b[j];
    acc += f[0] * W[j] + f[1] * W[128 + j] + f[2] * W[256 + j] + f[3] * W[384 + j];
    xs[idx] = acc * nsrc[n];
  } else {
    int idx = (bid - 25000) * 256 + threadIdx.x;  // 4 * 16384
    int mat = idx >> 14, rem = idx & 16383;
    int k = rem >> 7, n = rem & 127;
    const float* Wsrc = (mat < 3) ? (Wg + mat * 16384) : Wo1;
    float v = Wsrc[k * 128 + n];
    unsigned short hi = f2bf(v);
    float lo = v - bf2f(hi);
    unsigned short* basep = wt + mat * 32768;
    basep[n * 128 + k] = hi;
    basep[16384 + n * 128 + k] = f2bf(lo);
  }
}

// ---------------- SpMM: a[n] = ndst[n]*sum xs[src]; write bf16 hi/lo split ----------------
__global__ __launch_bounds__(256) void k_spmm(const float* __restrict__ xs,
                                              unsigned short* __restrict__ ahi,
                                              unsigned short* __restrict__ alo,
                                              const int* __restrict__ col,
                                              const int* __restrict__ row_start,
                                              const int* __restrict__ in_cnt,
                                              const float* __restrict__ ndst) {
  int node = blockIdx.x * 4 + (threadIdx.x >> 6);
  int lane = threadIdx.x & 63;
  int half = lane >> 5;
  int ql = lane & 31;
  int start = row_start[node];
  int cnt = in_cnt[node];
  float4 acc = make_float4(0.f, 0.f, 0.f, 0.f);
  const float4* X4 = (const float4*)xs;
  for (int base = 0; base < cnt; base += 64) {
    int m = min(cnt - base, 64);
    int ccol = (lane < m) ? col[start + base + lane] : 0;
    for (int jj = 0; jj < m; jj += 8) {
      int i0 = jj + half, i1 = i0 + 2, i2 = i0 + 4, i3 = i0 + 6;
      int mm = m - 1;
      int s0 = __shfl(ccol, min(i0, mm));
      int s1 = __shfl(ccol, min(i1, mm));
      int s2 = __shfl(ccol, min(i2, mm));
      int s3 = __shfl(ccol, min(i3, mm));
      float f0 = (i0 < m) ? 1.f : 0.f;
      float f1 = (i1 < m) ? 1.f : 0.f;
      float f2 = (i2 < m) ? 1.f : 0.f;
      float f3 = (i3 < m) ? 1.f : 0.f;
      float4 v0 = X4[(size_t)s0 * 32 + ql];
      float4 v1 = X4[(size_t)s1 * 32 + ql];
      float4 v2 = X4[(size_t)s2 * 32 + ql];
      float4 v3 = X4[(size_t)s3 * 32 + ql];
      acc.x = fmaf(f0, v0.x, acc.x); acc.y = fmaf(f0, v0.y, acc.y);
      acc.z = fmaf(f0, v0.z, acc.z); acc.w = fmaf(f0, v0.w, acc.w);
      acc.x = fmaf(f1, v1.x, acc.x); acc.y = fmaf(f1, v1.y, acc.y);
      acc.z = fmaf(f1, v1.z, acc.z); acc.w = fmaf(f1, v1.w, acc.w);
      acc.x = fmaf(f2, v2.x, acc.x); acc.y = fmaf(f2, v2.y, acc.y);
      acc.z = fmaf(f2, v2.z, acc.z); acc.w = fmaf(f2, v2.w, acc.w);
      acc.x = fmaf(f3, v3.x, acc.x); acc.y = fmaf(f3, v3.y, acc.y);
      acc.z = fmaf(f3, v3.z, acc.z); acc.w = fmaf(f3, v3.w, acc.w);
    }
  }
  acc.x += __shfl_down(acc.x, 32);
  acc.y += __shfl_down(acc.y, 32);
  acc.z += __shfl_down(acc.z, 32);
  acc.w += __shfl_down(acc.w, 32);
  if (half == 0) {
    float nd = ndst[node];
    float v0 = acc.x * nd, v1 = acc.y * nd, v2 = acc.z * nd, v3 = acc.w * nd;
    ushort4 h, l;
    h.x = f2bf(v0); l.x = f2bf(v0 - bf2f(h.x));
    h.y = f2bf(v1); l.y = f2bf(v1 - bf2f(h.y));
    h.z = f2bf(v2); l.z = f2bf(v2 - bf2f(h.z));
    h.w = f2bf(v3); l.w = f2bf(v3 - bf2f(h.w));
    *(ushort4*)(ahi + (size_t)node * 128 + ql * 4) = h;
    *(ushort4*)(alo + (size_t)node * 128 + ql * 4) = l;
  }
}

// ---------------- MFMA GEMM (bf16x3 split): out = relu(A @ Wt^T + bias) ----------------
// modes: 0 = write fp32 * nsrc (xs), 1 = write bf16 hi/lo, 3 = fused final dot with W_o2
__global__ __launch_bounds__(256) void k_gemm_mfma(
    const unsigned short* __restrict__ Ahi, const unsigned short* __restrict__ Alo,
    const unsigned short* __restrict__ Wth, const unsigned short* __restrict__ Wtl,
    const float* __restrict__ bias, float* __restrict__ outf,
    unsigned short* __restrict__ outhi, unsigned short* __restrict__ outlo,
    const float* __restrict__ nsrc, const float* __restrict__ W_o2,
    const float* __restrict__ b_o2, int M, int mode) {
  __shared__ unsigned short sm[2 * 64 * 128];  // Ah (16KB) then Al (16KB)
  __shared__ float smred[4][64];
  int tid = threadIdx.x;
  int lane = tid & 63, w = tid >> 6;
  int tile0 = blockIdx.x * 64;

  {
    int slot = lane & 15;
#pragma unroll
    for (int j = 0; j < 4; ++j) {
      int ldsoff = w * 4096 + j * 1024;
      int row = (ldsoff >> 8) + (lane >> 4);
      int grow = tile0 + row;
      if (grow > M - 1) grow = M - 1;
      size_t gsrc = (size_t)grow * 256 + (size_t)(((slot ^ (row & 7)) << 4));
      gload16((const char*)Ahi + gsrc, (char*)sm + ldsoff);
      gload16((const char*)Alo + gsrc, (char*)sm + 16384 + ldsoff);
    }
  }

  bf16x8 bh[2][4], bl[2][4];
  {
    int koff = (lane >> 4) * 8;
#pragma unroll
    for (int cf = 0; cf < 2; ++cf) {
      int n = w * 32 + cf * 16 + (lane & 15);
      const unsigned short* ph = Wth + (size_t)n * 128 + koff;
      const unsigned short* pl = Wtl + (size_t)n * 128 + koff;
#pragma unroll
      for (int kc = 0; kc < 4; ++kc) {
        bh[cf][kc] = *(const bf16x8*)(ph + kc * 32);
        bl[cf][kc] = *(const bf16x8*)(pl + kc * 32);
      }
    }
  }

  f32x4 acc[4][2] = {};
  __syncthreads();

  int r15 = lane & 15, kq = lane >> 4;
  for (int kc = 0; kc < 4; ++kc) {
    bf16x8 ah[4], al[4];
#pragma unroll
    for (int m = 0; m < 4; ++m) {
      int row = m * 16 + r15;
      int boff = row * 256 + ((((kc * 4 + kq) ^ (row & 7))) << 4);
      ah[m] = *(const bf16x8*)((const char*)sm + boff);
      al[m] = *(const bf16x8*)((const char*)sm + 16384 + boff);
    }
#pragma unroll
    for (int m = 0; m < 4; ++m)
#pragma unroll
      for (int cf = 0; cf < 2; ++cf) {
        acc[m][cf] = __builtin_amdgcn_mfma_f32_16x16x32_bf16(ah[m], bh[cf][kc], acc[m][cf], 0, 0, 0);
        acc[m][cf] = __builtin_amdgcn_mfma_f32_16x16x32_bf16(ah[m], bl[cf][kc], acc[m][cf], 0, 0, 0);
        acc[m][cf] = __builtin_amdgcn_mfma_f32_16x16x32_bf16(al[m], bh[cf][kc], acc[m][cf], 0, 0, 0);
      }
  }

  if (mode == 3) {
    float w2v[2], bv2[2];
#pragma unroll
    for (int cf = 0; cf < 2; ++cf) {
      int colg = w * 32 + cf * 16 + r15;
      w2v[cf] = W_o2[colg];
      bv2[cf] = bias[colg];
    }
#pragma unroll
    for (int m = 0; m < 4; ++m) {
#pragma unroll
      for (int i = 0; i < 4; ++i) {
        float p = fmaxf(acc[m][0][i] + bv2[0], 0.f) * w2v[0] +
                  fmaxf(acc[m][1][i] + bv2[1], 0.f) * w2v[1];
#pragma unroll
        for (int msk = 1; msk < 16; msk <<= 1) p += __shfl_xor(p, msk);
        if (r15 == 0) smred[w][m * 16 + kq * 4 + i] = p;
      }
    }
    __syncthreads();
    if (tid < 64) {
      int gr = tile0 + tid;
      if (gr < M)
        outf[gr] = smred[0][tid] + smred[1][tid] + smred[2][tid] + smred[3][tid] + b_o2[0];
    }
    return;
  }
#pragma unroll
  for (int cf = 0; cf < 2; ++cf) {
    int colg = w * 32 + cf * 16 + r15;
    float bv = bias[colg];
#pragma unroll
    for (int m = 0; m < 4; ++m) {
#pragma unroll
      for (int i = 0; i < 4; ++i) {
        int gr = tile0 + m * 16 + kq * 4 + i;
        if (gr < M) {
          float v = fmaxf(acc[m][cf][i] + bv, 0.f);
          if (mode == 0) {
            outf[(size_t)gr * 128 + colg] = v * nsrc[gr];
          } else {
            unsigned short h = f2bf(v);
            outhi[(size_t)gr * 128 + colg] = h;
            outlo[(size_t)gr * 128 + colg] = f2bf(v - bf2f(h));
          }
        }
      }
    }
  }
}

extern "C" void kernel_launch(void* const* d_in, const int* in_sizes, int n_in,
                              void* d_out, int out_size, void* d_ws, size_t ws_size,
                              hipStream_t stream) {
  const float* node_feats = (const float*)d_in[0];
  const int* src = (const int*)d_in[1];
  const int* dst = (const int*)d_in[2];
  const float* W_emb = (const float*)d_in[3];
  const float* b_emb = (const float*)d_in[4];
  const float* W_g = (const float*)d_in[5];
  const float* b_g = (const float*)d_in[6];
  const float* W_o1 = (const float*)d_in[7];
  const float* b_o1 = (const float*)d_in[8];
  const float* W_o2 = (const float*)d_in[9];
  const float* b_o2 = (const float*)d_in[10];
  float* out = (float*)d_out;

  // Workspace layout (bytes); hist_out/hist_in alias the X region (dead
  // until k_embed_prep, which runs after k_fill).
  char* ws = (char*)d_ws;
  int* in_cnt    = (int*)(ws + 0);                        // 200,704
  int* row_start = (int*)(ws + 200704);                   // 200,704
  float* nsrc    = (float*)(ws + 401408);                 // 200,704
  float* ndst    = (float*)(ws + 602112);                 // 200,704
  int* bsum      = (int*)(ws + 802816);                   // 1,024
  int* col       = (int*)(ws + 803840);                   // 2,560,000
  unsigned short* wt = (unsigned short*)(ws + 3363840);   // 262,144
  float* X       = (float*)(ws + 3625984);                // 25,600,000
  unsigned short* Xu = (unsigned short*)(ws + 3625984);
  unsigned short* hist_out = (unsigned short*)(ws + 3625984);            // 6,422,528 (in X)
  unsigned short* hist_in  = (unsigned short*)(ws + 3625984 + 6422528);  // 12,845,056 (in X)
  unsigned short* Ahi = (unsigned short*)(ws + 29225984); // 12,800,000
  unsigned short* Alo = (unsigned short*)(ws + 42025984); // 12,800,000 -> ends 54,825,984

  // No memset needed: all counters live in LDS and are zeroed in-kernel.
  k_hist<<<OUT_CHUNKS + IN_CHUNKS, 256, 0, stream>>>(src, dst, hist_out, hist_in);
  k_scan1<<<SCAN_B, 256, 0, stream>>>(hist_out, hist_in, nsrc, ndst, in_cnt, bsum);
  k_scan3<<<SCAN_B, 256, 0, stream>>>(in_cnt, bsum, row_start);
  k_fill<<<IN_CHUNKS, 256, 0, stream>>>(src, dst, row_start, hist_in, col);
  k_embed_prep<<<25256, 256, 0, stream>>>(node_feats, W_emb, b_emb, nsrc, X,
                                          W_g, W_o1, wt);

  int gemm_grid = (NN + 63) / 64;
  for (int l = 0; l < 3; ++l) {
    k_spmm<<<NN / 4, 256, 0, stream>>>(X, Ahi, Alo, col, row_start, in_cnt, ndst);
    unsigned short* wth = wt + l * 32768;
    unsigned short* wtl = wth + 16384;
    if (l < 2) {
      k_gemm_mfma<<<gemm_grid, 256, 0, stream>>>(Ahi, Alo, wth, wtl, b_g + l * 128,
                                                 X, nullptr, nullptr, nsrc,
                                                 nullptr, nullptr, NN, 0);
    } else {
      k_gemm_mfma<<<gemm_grid, 256, 0, stream>>>(Ahi, Alo, wth, wtl, b_g + l * 128,
                                                 nullptr, Xu, Xu + 6400000, nsrc,
                                                 nullptr, nullptr, NN, 1);
    }
  }
  k_gemm_mfma<<<gemm_grid, 256, 0, stream>>>(Xu, Xu + 6400000, wt + 3 * 32768,
                                             wt + 3 * 32768 + 16384, b_o1,
                                             out, nullptr, nullptr, nsrc,
                                             W_o2, b_o2, NN, 3);
}